// Round 12
// baseline (304.302 us; speedup 1.0000x reference)
//
#include <hip/hip_runtime.h>

#define D 128
#define CPAD 32

typedef __attribute__((ext_vector_type(8)))  short s16x8;
typedef __attribute__((ext_vector_type(4)))  short s16x4;
typedef __attribute__((ext_vector_type(16))) float f32x16;

static __device__ __forceinline__ unsigned short f2bf(float x) {
    unsigned u = __builtin_bit_cast(unsigned, x);
    unsigned r = (u + 0x7FFF + ((u >> 16) & 1)) >> 16;   // RNE
    return (unsigned short)r;
}
static __device__ __forceinline__ float bf2f(unsigned short h) {
    unsigned u = ((unsigned)h) << 16;
    return __builtin_bit_cast(float, u);
}
static __device__ __forceinline__ float bflo(unsigned v) {
    return __builtin_bit_cast(float, v << 16);
}
static __device__ __forceinline__ float bfhi(unsigned v) {
    return __builtin_bit_cast(float, v & 0xFFFF0000u);
}

// ---------------- zero (must precede fat kernel's count part) ----------------

__global__ void zero_pad_kernel(int* __restrict__ a, int* __restrict__ b, int n4) {
    int i = blockIdx.x * blockDim.x + threadIdx.x;
    if (i < n4) {
        *(int4*)(a + i * 4) = make_int4(0, 0, 0, 0);
        *(int4*)(b + i * 4) = make_int4(0, 0, 0, 0);
    }
}

// ---------------- fat pre-kernel: {count_rank | split_rows | tobf16 | prep_weights} ----------------
// Round-11 lesson: fusion != overlap — atomics contend with loads at L2, the
// kernel runs at the atomic wall + BW time (72us ~= serial sum). Kept fused
// (fewer launches); the structural fix is removing the atomics (radix CSR).

__global__ __launch_bounds__(256) void fat_pre_kernel(
    const int* __restrict__ hf_dst, const int* __restrict__ tt_dst,
    int* __restrict__ deg_hf, int* __restrict__ deg_tt,
    unsigned short* __restrict__ rank_hf, unsigned short* __restrict__ rank_tt,
    int E1, int E2, int nbc,
    const float* __restrict__ h_station,
    unsigned short* __restrict__ st_h, unsigned short* __restrict__ st_l,
    int ns_elem, int nbs,
    const float* __restrict__ h_feature, unsigned short* __restrict__ feat_h,
    int nf_elem, int nbf,
    const float* __restrict__ Wself, const float* __restrict__ Wneigh,
    short* __restrict__ wt)
{
    int b = blockIdx.x;
    int tid = threadIdx.x;
    if (b < nbc) {
        int i = b * 256 + tid;
        if (i < E1) {
            int r = atomicAdd(&deg_hf[hf_dst[i] * CPAD], 1);
            rank_hf[i] = (unsigned short)r;
        }
        if (i < E2) {
            int r = atomicAdd(&deg_tt[tt_dst[i] * CPAD], 1);
            rank_tt[i] = (unsigned short)r;
        }
        return;
    }
    b -= nbc;
    if (b < nbs) {
        int i = (b * 256 + tid) * 4;
        if (i < ns_elem) {
            float4 v = *(const float4*)(h_station + i);
            s16x4 hv, lv;
            unsigned short h0 = f2bf(v.x); hv[0] = (short)h0; lv[0] = (short)f2bf(v.x - bf2f(h0));
            unsigned short h1 = f2bf(v.y); hv[1] = (short)h1; lv[1] = (short)f2bf(v.y - bf2f(h1));
            unsigned short h2 = f2bf(v.z); hv[2] = (short)h2; lv[2] = (short)f2bf(v.z - bf2f(h2));
            unsigned short h3 = f2bf(v.w); hv[3] = (short)h3; lv[3] = (short)f2bf(v.w - bf2f(h3));
            *(s16x4*)(st_h + i) = hv;
            *(s16x4*)(st_l + i) = lv;
        }
        return;
    }
    b -= nbs;
    if (b < nbf) {
        int i = (b * 256 + tid) * 4;
        if (i < nf_elem) {
            float4 v = *(const float4*)(h_feature + i);
            s16x4 hv;
            hv[0] = (short)f2bf(v.x);
            hv[1] = (short)f2bf(v.y);
            hv[2] = (short)f2bf(v.z);
            hv[3] = (short)f2bf(v.w);
            *(s16x4*)(feat_h + i) = hv;
        }
        return;
    }
    b -= nbf;
    {
        int g = b * 256 + tid;               // [0, 16384)
        int m = g >> 11;
        int e = g & 2047;
        int n  = e >> 4;
        int kg = e & 15;
        int kk0 = kg >> 3;
        int kl0 = (kg & 7) * 8;
        int pair = m >> 1, s = m & 1;
        int l = (pair == 3) ? 2 : ((pair == 2) ? 1 : 0);
        int r = (pair == 0) ? 0 : 1;
        const float* W = (s ? Wneigh : Wself) + (size_t)(l * 2 + r) * D * D;
        s16x8 hv;
        #pragma unroll
        for (int c = 0; c < 8; ++c) {
            int k = kk0 * 64 + kl0 + c;
            hv[c] = (short)f2bf(W[(size_t)k * D + n]);
        }
        int ksb = kl0 ^ ((n & 7) << 3);
        size_t base = ((size_t)(pair * 2 + s) * 2 + kk0) * 8192;
        *(s16x8*)&wt[base + n * 64 + ksb] = hv;
    }
}

#define SCAN_EPB 1024

__global__ __launch_bounds__(256) void scan_blocks_kernel(
    const int* __restrict__ deg_hf, int* __restrict__ rp_hf, int* __restrict__ bs_hf,
    const int* __restrict__ deg_tt, int* __restrict__ rp_tt, int* __restrict__ bs_tt,
    int n, int nb)
{
    int gid = blockIdx.x;
    const int* deg; int* rp; int* bs; int b;
    if (gid < nb) { deg = deg_hf; rp = rp_hf; bs = bs_hf; b = gid; }
    else         { deg = deg_tt; rp = rp_tt; bs = bs_tt; b = gid - nb; }
    int t = threadIdx.x;
    int i0 = b * SCAN_EPB + t * 4;
    int4 v = make_int4(0, 0, 0, 0);
    if (i0 + 0 < n) v.x = deg[(size_t)(i0 + 0) * CPAD];
    if (i0 + 1 < n) v.y = deg[(size_t)(i0 + 1) * CPAD];
    if (i0 + 2 < n) v.z = deg[(size_t)(i0 + 2) * CPAD];
    if (i0 + 3 < n) v.w = deg[(size_t)(i0 + 3) * CPAD];
    __shared__ int sm[256];
    sm[t] = v.x + v.y + v.z + v.w;
    __syncthreads();
    for (int off = 1; off < 256; off <<= 1) {
        int x = (t >= off) ? sm[t - off] : 0;
        __syncthreads();
        sm[t] += x;
        __syncthreads();
    }
    int excl = (t > 0) ? sm[t - 1] : 0;
    if (i0 + 0 < n) rp[i0 + 0] = excl;
    if (i0 + 1 < n) rp[i0 + 1] = excl + v.x;
    if (i0 + 2 < n) rp[i0 + 2] = excl + v.x + v.y;
    if (i0 + 3 < n) rp[i0 + 3] = excl + v.x + v.y + v.z;
    if (t == 255) bs[b] = sm[255];
}

__global__ __launch_bounds__(256) void scan_offsets_kernel(
    int* __restrict__ rp_hf, const int* __restrict__ bs_hf,
    int* __restrict__ rp_tt, const int* __restrict__ bs_tt,
    int n, int nb, int E1, int E2)
{
    int gid = blockIdx.x;
    int* rp; const int* bs; int b; int E;
    if (gid < nb) { rp = rp_hf; bs = bs_hf; b = gid; E = E1; }
    else         { rp = rp_tt; bs = bs_tt; b = gid - nb; E = E2; }
    int t = threadIdx.x;
    int lane = t & 63;
    int partial = 0;
    for (int i = lane; i < b; i += 64) partial += bs[i];
    #pragma unroll
    for (int off = 32; off; off >>= 1) partial += __shfl_xor(partial, off);
    if (b == 0 && t == 0) rp[n] = E;
    if (partial == 0) return;
    int i0 = b * SCAN_EPB + t * 4;
    if (i0 + 0 < n) rp[i0 + 0] += partial;
    if (i0 + 1 < n) rp[i0 + 1] += partial;
    if (i0 + 2 < n) rp[i0 + 2] += partial;
    if (i0 + 3 < n) rp[i0 + 3] += partial;
}

__global__ void fill_both_kernel(
    const int* __restrict__ hf_src, const int* __restrict__ hf_dst,
    const unsigned short* __restrict__ rank_hf,
    const int* __restrict__ rp_hf, int* __restrict__ col_hf,
    const int* __restrict__ tt_src, const int* __restrict__ tt_dst,
    const unsigned short* __restrict__ rank_tt,
    const int* __restrict__ rp_tt, int* __restrict__ col_tt,
    int E1, int E2) {
    int i0 = (blockIdx.x * blockDim.x + threadIdx.x) * 4;
    if (i0 + 3 < E1) {
        int4 d = *(const int4*)(hf_dst + i0);
        int4 s = *(const int4*)(hf_src + i0);
        ushort4 r = *(const ushort4*)(rank_hf + i0);
        int p0 = rp_hf[d.x], p1 = rp_hf[d.y], p2 = rp_hf[d.z], p3 = rp_hf[d.w];
        col_hf[p0 + r.x] = s.x;
        col_hf[p1 + r.y] = s.y;
        col_hf[p2 + r.z] = s.z;
        col_hf[p3 + r.w] = s.w;
    } else {
        for (int j = 0; j < 4 && i0 + j < E1; ++j)
            col_hf[rp_hf[hf_dst[i0 + j]] + rank_hf[i0 + j]] = hf_src[i0 + j];
    }
    if (i0 + 3 < E2) {
        int4 d = *(const int4*)(tt_dst + i0);
        int4 s = *(const int4*)(tt_src + i0);
        ushort4 r = *(const ushort4*)(rank_tt + i0);
        int p0 = rp_tt[d.x], p1 = rp_tt[d.y], p2 = rp_tt[d.z], p3 = rp_tt[d.w];
        col_tt[p0 + r.x] = s.x;
        col_tt[p1 + r.y] = s.y;
        col_tt[p2 + r.z] = s.z;
        col_tt[p3 + r.w] = s.w;
    } else {
        for (int j = 0; j < 4 && i0 + j < E2; ++j)
            col_tt[rp_tt[tt_dst[i0 + j]] + rank_tt[i0 + j]] = tt_src[i0 + j];
    }
}

// ---------------- segment mean: paired-row 8B/lane gather, bf16-hi output ----------------
// Wave halves (lanes 0-31 / 32-63) gather two different edges per step with
// uint2 (4 bf16) loads -> 2x bytes in flight per outstanding load. shfl_xor(32)
// merges halves; 32-lane coalesced 8B stores.

__global__ __launch_bounds__(256) void agg_mean_kernel(
    const unsigned short* __restrict__ hsrc, const int* __restrict__ rowptr,
    const int* __restrict__ col, unsigned short* __restrict__ oh, int ndst) {
    int w = (blockIdx.x * blockDim.x + threadIdx.x) >> 6;
    int lane = threadIdx.x & 63;
    if (w >= ndst) return;
    int beg = rowptr[w];
    int end = rowptr[w + 1];
    int deg = end - beg;
    const int half = lane >> 5;
    const int c4 = (lane & 31) * 4;     // ushort index of this lane's 4 columns

    float a0[8], a1[8], a2[8], a3[8];
    #pragma unroll
    for (int u = 0; u < 8; ++u) { a0[u] = 0.f; a1[u] = 0.f; a2[u] = 0.f; a3[u] = 0.f; }

    for (int b = beg; b < end; b += 64) {
        int n = min(64, end - b);
        int myidx = (lane < n) ? col[b + lane] : 0;
        int j = 0;
        for (; j + 16 <= n; j += 16) {
            #pragma unroll
            for (int u = 0; u < 8; ++u) {
                int i0 = __shfl(myidx, j + 2 * u);
                int i1 = __shfl(myidx, j + 2 * u + 1);
                int s = half ? i1 : i0;
                uint2 v = *(const uint2*)(hsrc + (size_t)s * D + c4);
                a0[u] += bflo(v.x); a1[u] += bfhi(v.x);
                a2[u] += bflo(v.y); a3[u] += bfhi(v.y);
            }
        }
        for (; j + 2 <= n; j += 2) {
            int i0 = __shfl(myidx, j);
            int i1 = __shfl(myidx, j + 1);
            int s = half ? i1 : i0;
            uint2 v = *(const uint2*)(hsrc + (size_t)s * D + c4);
            a0[0] += bflo(v.x); a1[0] += bfhi(v.x);
            a2[0] += bflo(v.y); a3[0] += bfhi(v.y);
        }
        if (j < n) {   // odd tail: low half only
            int i0 = __shfl(myidx, j);
            if (!half) {
                uint2 v = *(const uint2*)(hsrc + (size_t)i0 * D + c4);
                a0[0] += bflo(v.x); a1[0] += bfhi(v.x);
                a2[0] += bflo(v.y); a3[0] += bfhi(v.y);
            }
        }
    }
    float s0 = ((a0[0] + a0[1]) + (a0[2] + a0[3])) + ((a0[4] + a0[5]) + (a0[6] + a0[7]));
    float s1 = ((a1[0] + a1[1]) + (a1[2] + a1[3])) + ((a1[4] + a1[5]) + (a1[6] + a1[7]));
    float s2 = ((a2[0] + a2[1]) + (a2[2] + a2[3])) + ((a2[4] + a2[5]) + (a2[6] + a2[7]));
    float s3 = ((a3[0] + a3[1]) + (a3[2] + a3[3])) + ((a3[4] + a3[5]) + (a3[6] + a3[7]));
    s0 += __shfl_xor(s0, 32);
    s1 += __shfl_xor(s1, 32);
    s2 += __shfl_xor(s2, 32);
    s3 += __shfl_xor(s3, 32);
    if (!half) {
        float inv = 1.0f / fmaxf((float)deg, 1.0f);
        ushort4 o;
        o.x = f2bf(s0 * inv);
        o.y = f2bf(s1 * inv);
        o.z = f2bf(s2 * inv);
        o.w = f2bf(s3 * inv);
        *(ushort4*)(oh + (size_t)w * D + c4) = o;
    }
}

// ---------------- fused SAGE layer: 2-term split, neighbor bf16-only, 2-deep prefetch ----------------
// Y = relu(Aself@W1 + N@W2 + bias); A exact (hi+lo, 2 MFMA), N bf16 (1 MFMA).
// Stages: 0,1 = self k-halves; 2,3 = neighbor k-halves. Named reg sets rgA/rgB
// (rule #20: no runtime-indexed reg arrays), loads issued 2 stages ahead.

struct Regs { s16x8 a0, a1, a2, a3, b0, b1, b2, b3; };

template<bool ACC, bool WF32, bool WBF>
__global__ __launch_bounds__(256) void sage_mfma_kernel(
    const unsigned short* __restrict__ Ah_g, const unsigned short* __restrict__ Al_g,
    const unsigned short* __restrict__ Nh_g,
    const short* __restrict__ wtp, const float* __restrict__ bias,
    float* __restrict__ Yf, unsigned short* __restrict__ Yh, unsigned short* __restrict__ Yl,
    int M)
{
    __shared__ short lds[16384];   // 32KB: Ah[0:4k] Al[4k:8k] Bh[8k:16k]
    short* AhS = lds;
    short* AlS = lds + 4096;
    short* BhS = lds + 8192;

    const int tid = threadIdx.x;
    const int l = tid & 63, w = tid >> 6;
    const int wr = w >> 1, wc = w & 1;
    const int row0 = blockIdx.x * 64;

    f32x16 acc[2] = {};

    const int s_row = tid >> 2;
    const int s_k   = (tid & 3) * 16;
    const int s_sw  = (s_row & 7) << 3;
    const int arow  = wr * 32 + (l & 31);
    const int fsw   = (l & 7) << 3;
    const int afk   = (l >> 5) * 8;

    Regs rgA, rgB;

    auto issue = [&](Regs& rg, int st, bool self) {
        const unsigned short* Hg = self ? Ah_g : Nh_g;
        const unsigned short* hrow = Hg + (size_t)(row0 + s_row) * D + (st & 1) * 64 + s_k;
        rg.a0 = *(const s16x8*)(hrow);
        rg.a1 = *(const s16x8*)(hrow + 8);
        if (self) {
            const unsigned short* lrow = Al_g + (size_t)(row0 + s_row) * D + (st & 1) * 64 + s_k;
            rg.a2 = *(const s16x8*)(lrow);
            rg.a3 = *(const s16x8*)(lrow + 8);
        }
        const short* wsrc = wtp + (size_t)st * 8192;
        rg.b0 = *(const s16x8*)(wsrc + tid * 8);
        rg.b1 = *(const s16x8*)(wsrc + 2048 + tid * 8);
        rg.b2 = *(const s16x8*)(wsrc + 4096 + tid * 8);
        rg.b3 = *(const s16x8*)(wsrc + 6144 + tid * 8);
    };
    auto commit = [&](Regs& rg, bool self) {
        *(s16x8*)&AhS[s_row * 64 + (s_k ^ s_sw)]       = rg.a0;
        *(s16x8*)&AhS[s_row * 64 + ((s_k + 8) ^ s_sw)] = rg.a1;
        if (self) {
            *(s16x8*)&AlS[s_row * 64 + (s_k ^ s_sw)]       = rg.a2;
            *(s16x8*)&AlS[s_row * 64 + ((s_k + 8) ^ s_sw)] = rg.a3;
        }
        *(s16x8*)&BhS[tid * 8]        = rg.b0;
        *(s16x8*)&BhS[2048 + tid * 8] = rg.b1;
        *(s16x8*)&BhS[4096 + tid * 8] = rg.b2;
        *(s16x8*)&BhS[6144 + tid * 8] = rg.b3;
    };
    auto domfma = [&](bool self) {
        #pragma unroll
        for (int kc = 0; kc < 4; ++kc) {
            int ak = (kc * 16 + afk) ^ fsw;
            s16x8 ah = *(const s16x8*)&AhS[arow * 64 + ak];
            s16x8 al;
            if (self) al = *(const s16x8*)&AlS[arow * 64 + ak];
            #pragma unroll
            for (int nt = 0; nt < 2; ++nt) {
                int brow = wc * 64 + nt * 32 + (l & 31);
                s16x8 bh = *(const s16x8*)&BhS[brow * 64 + ak];
                acc[nt] = __builtin_amdgcn_mfma_f32_32x32x16_bf16(ah, bh, acc[nt], 0, 0, 0);
                if (self)
                    acc[nt] = __builtin_amdgcn_mfma_f32_32x32x16_bf16(al, bh, acc[nt], 0, 0, 0);
            }
        }
    };

    issue(rgA, 0, true);
    issue(rgB, 1, true);
    // st0 (self)
    __syncthreads(); commit(rgA, true);  issue(rgA, 2, false);
    __syncthreads(); domfma(true);
    // st1 (self)
    __syncthreads(); commit(rgB, true);  issue(rgB, 3, false);
    __syncthreads(); domfma(true);
    // st2 (neigh)
    __syncthreads(); commit(rgA, false);
    __syncthreads(); domfma(false);
    // st3 (neigh)
    __syncthreads(); commit(rgB, false);
    __syncthreads(); domfma(false);

    // ---- epilogue: acc -> fp32 LDS stage -> coalesced global IO ----
    __syncthreads();
    float* fstage = (float*)lds;
    const int colb = l & 31;
    const int rq4  = (l >> 5) * 4;
    #pragma unroll
    for (int nt = 0; nt < 2; ++nt) {
        int col = wc * 64 + nt * 32 + colb;
        float bias_c = bias[col];
        #pragma unroll
        for (int g = 0; g < 4; ++g) {
            #pragma unroll
            for (int q = 0; q < 4; ++q) {
                int r = wr * 32 + q + g * 8 + rq4;
                fstage[r * 128 + col] = fmaxf(acc[nt][g * 4 + q] + bias_c, 0.f);
            }
        }
    }
    __syncthreads();
    int orow = tid >> 2;
    int ocol = (tid & 3) * 32;
    int grow = row0 + orow;
    if (grow < M) {
        float vals[32];
        #pragma unroll
        for (int c = 0; c < 32; c += 4)
            *(float4*)&vals[c] = *(const float4*)&fstage[orow * 128 + ocol + c];
        size_t base = (size_t)grow * D + ocol;
        if (ACC) {
            #pragma unroll
            for (int c8 = 0; c8 < 4; ++c8) {
                s16x8 oh = *(const s16x8*)(Yh + base + c8 * 8);
                s16x8 ol = *(const s16x8*)(Yl + base + c8 * 8);
                #pragma unroll
                for (int e = 0; e < 8; ++e)
                    vals[c8 * 8 + e] += bf2f((unsigned short)oh[e]) + bf2f((unsigned short)ol[e]);
            }
        }
        if (WF32) {
            #pragma unroll
            for (int c = 0; c < 32; c += 4)
                *(float4*)(Yf + base + c) = *(const float4*)&vals[c];
        }
        if (WBF) {
            #pragma unroll
            for (int c8 = 0; c8 < 4; ++c8) {
                s16x8 hv, lv;
                #pragma unroll
                for (int e = 0; e < 8; ++e) {
                    float v = vals[c8 * 8 + e];
                    unsigned short h = f2bf(v);
                    hv[e] = (short)h;
                    lv[e] = (short)f2bf(v - bf2f(h));
                }
                *(s16x8*)(Yh + base + c8 * 8) = hv;
                *(s16x8*)(Yl + base + c8 * 8) = lv;
            }
        }
    }
}

// ---------------- launch ----------------

extern "C" void kernel_launch(void* const* d_in, const int* in_sizes, int n_in,
                              void* d_out, int out_size, void* d_ws, size_t ws_size,
                              hipStream_t stream) {
    const float* h_station = (const float*)d_in[0];
    const float* h_feature = (const float*)d_in[1];
    const float* Wself     = (const float*)d_in[2];
    const float* Wneigh    = (const float*)d_in[3];
    const float* bias      = (const float*)d_in[4];
    const int* hf_src = (const int*)d_in[5];
    const int* hf_dst = (const int*)d_in[6];
    const int* tt_src = (const int*)d_in[7];
    const int* tt_dst = (const int*)d_in[8];

    const int NS = in_sizes[0] / D;
    const int NF = in_sizes[1] / D;
    const int E1 = in_sizes[5];
    const int E2 = in_sizes[7];
    const int NSP = (NS + 63) & ~63;

    char* ws = (char*)d_ws;
    size_t off = 0;
    auto alloc = [&](size_t bytes) -> void* {
        void* p = ws + off;
        off = (off + bytes + 255) & ~(size_t)255;
        return p;
    };
    unsigned short* st_h  = (unsigned short*)alloc((size_t)NSP * D * 2);
    unsigned short* st_l  = (unsigned short*)alloc((size_t)NSP * D * 2);
    unsigned short* n_h   = (unsigned short*)alloc((size_t)NSP * D * 2);
    unsigned short* n_l   = (unsigned short*)alloc((size_t)NSP * D * 2);   // deg_tt backing only
    unsigned short* hb_h  = (unsigned short*)alloc((size_t)NSP * D * 2 * 2);
    unsigned short* hb_l  = hb_h + (size_t)NSP * D;
    int* rp_hf    = (int*)alloc((size_t)(NS + 1) * sizeof(int));
    int* col_hf   = (int*)alloc((size_t)E1 * sizeof(int));
    int* rp_tt    = (int*)alloc((size_t)(NS + 1) * sizeof(int));
    int* col_tt   = (int*)alloc((size_t)E2 * sizeof(int));
    unsigned short* rank_hf = (unsigned short*)alloc((size_t)E1 * 2);
    unsigned short* rank_tt = (unsigned short*)alloc((size_t)E2 * 2);
    int  nb       = (NS + SCAN_EPB - 1) / SCAN_EPB;
    int* bs_hf    = (int*)alloc((size_t)nb * sizeof(int));
    int* bs_tt    = (int*)alloc((size_t)nb * sizeof(int));
    short* wt     = (short*)alloc((size_t)4 * 32768 * sizeof(short));

    // aliases (time-disjoint, stream-ordered):
    int* deg_hf = (int*)n_h;
    int* deg_tt = (int*)n_l;
    unsigned short* feat_h = hb_h;

    const int tpb = 256;
    int ge4  = ((max(E1, E2) + 3) / 4 + tpb - 1) / tpb;
    int gzp  = ((NS * CPAD / 4) + tpb - 1) / tpb;

    int nbc = (max(E1, E2) + tpb - 1) / tpb;
    int nbs = (NS * D / 4 + tpb - 1) / tpb;
    int nbf = (NF * D / 4 + tpb - 1) / tpb;

    zero_pad_kernel<<<gzp, tpb, 0, stream>>>(deg_hf, deg_tt, NS * CPAD / 4);
    fat_pre_kernel<<<nbc + nbs + nbf + 64, tpb, 0, stream>>>(
        hf_dst, tt_dst, deg_hf, deg_tt, rank_hf, rank_tt, E1, E2, nbc,
        h_station, st_h, st_l, NS * D, nbs,
        h_feature, feat_h, NF * D, nbf,
        Wself, Wneigh, wt);
    scan_blocks_kernel<<<2 * nb, tpb, 0, stream>>>(deg_hf, rp_hf, bs_hf,
                                                   deg_tt, rp_tt, bs_tt, NS, nb);
    scan_offsets_kernel<<<2 * nb, tpb, 0, stream>>>(rp_hf, bs_hf, rp_tt, bs_tt,
                                                    NS, nb, E1, E2);
    fill_both_kernel<<<ge4, tpb, 0, stream>>>(hf_src, hf_dst, rank_hf, rp_hf, col_hf,
                                              tt_src, tt_dst, rank_tt, rp_tt, col_tt, E1, E2);

    int gagg  = (NS * 64 + tpb - 1) / tpb;
    int ggemm = NSP / 64;

    auto BI = [&](int lidx, int r) { return bias + (size_t)(lidx * 2 + r) * D; };
    auto WT = [&](int pair) { return wt + (size_t)pair * 32768; };

    float* out = (float*)d_out;

    // ---- layer 1 ----
    agg_mean_kernel<<<gagg, tpb, 0, stream>>>(feat_h, rp_hf, col_hf, n_h, NS);
    sage_mfma_kernel<false, false, true><<<ggemm, tpb, 0, stream>>>(
        st_h, st_l, n_h, WT(0), BI(0,0), nullptr, hb_h, hb_l, NS);
    agg_mean_kernel<<<gagg, tpb, 0, stream>>>(st_h, rp_tt, col_tt, n_h, NS);
    sage_mfma_kernel<true, false, true><<<ggemm, tpb, 0, stream>>>(
        st_h, st_l, n_h, WT(1), BI(0,1), nullptr, hb_h, hb_l, NS);

    // ---- layer 2 (in-place: blocks read only their own rows before writing) ----
    agg_mean_kernel<<<gagg, tpb, 0, stream>>>(hb_h, rp_tt, col_tt, n_h, NS);
    sage_mfma_kernel<false, false, true><<<ggemm, tpb, 0, stream>>>(
        hb_h, hb_l, n_h, WT(2), BI(1,1), nullptr, hb_h, hb_l, NS);

    // ---- layer 3 ----
    agg_mean_kernel<<<gagg, tpb, 0, stream>>>(hb_h, rp_tt, col_tt, n_h, NS);
    sage_mfma_kernel<false, true, false><<<ggemm, tpb, 0, stream>>>(
        hb_h, hb_l, n_h, WT(3), BI(2,1), out, nullptr, nullptr, NS);
}